// Round 10
// baseline (883.435 us; speedup 1.0000x reference)
//
#include <hip/hip_runtime.h>
#include <hip/hip_fp16.h>

constexpr float LN_EPS = 1e-5f;

typedef _Float16 f16x8 __attribute__((ext_vector_type(8)));
typedef float f32x4 __attribute__((ext_vector_type(4)));

__device__ __forceinline__ unsigned short f2h(float f) {
  return __half_as_ushort(__float2half_rn(f));
}
__device__ __forceinline__ unsigned int pk2h(float x, float y) {
  return (unsigned int)f2h(x) | ((unsigned int)f2h(y) << 16);
}
__device__ __forceinline__ __half2 u2h2(unsigned int u) {
  return *reinterpret_cast<__half2*>(&u);
}

#define NPB 256    // nodes per bucket (bucket = node >> 8)
#define CHUNK 4096 // edges per partition block

// ======== passA: per-chunk LDS histograms (dst-bucket & src-bucket) =======
__global__ __launch_bounds__(256) void passA_kernel(
    const int* __restrict__ src, const int* __restrict__ dst,
    int* __restrict__ cntD, int* __restrict__ cntS, int NB, int NBLK, int E) {
  extern __shared__ int sh[];  // 2*NB
  for (int j = threadIdx.x; j < 2 * NB; j += 256) sh[j] = 0;
  __syncthreads();
  const int blk = blockIdx.x;
  const int base = blk * CHUNK;
  const int end = min(base + CHUNK, E);
  const int cnt = end - base;
  const int nv = cnt >> 2;
  const int4* d4p = reinterpret_cast<const int4*>(dst + base);
  const int4* s4p = reinterpret_cast<const int4*>(src + base);
  for (int q = threadIdx.x; q < nv; q += 256) {
    int4 d4 = d4p[q];
    int4 s4 = s4p[q];
    atomicAdd(&sh[d4.x >> 8], 1); atomicAdd(&sh[d4.y >> 8], 1);
    atomicAdd(&sh[d4.z >> 8], 1); atomicAdd(&sh[d4.w >> 8], 1);
    atomicAdd(&sh[NB + (s4.x >> 8)], 1); atomicAdd(&sh[NB + (s4.y >> 8)], 1);
    atomicAdd(&sh[NB + (s4.z >> 8)], 1); atomicAdd(&sh[NB + (s4.w >> 8)], 1);
  }
  for (int i = (nv << 2) + threadIdx.x; i < cnt; i += 256) {
    atomicAdd(&sh[dst[base + i] >> 8], 1);
    atomicAdd(&sh[NB + (src[base + i] >> 8)], 1);
  }
  __syncthreads();
  for (int j = threadIdx.x; j < NB; j += 256) {
    cntD[j * NBLK + blk] = sh[j];
    cntS[j * NBLK + blk] = sh[NB + j];
  }
}

// ==== scan1: per-bucket exclusive scan over blocks (grid = 2*NB blocks) ===
__global__ __launch_bounds__(512) void scan1_kernel(
    const int* __restrict__ cntD, const int* __restrict__ cntS,
    int* __restrict__ offLD, int* __restrict__ offLS,
    int* __restrict__ totD, int* __restrict__ totS, int NB, int NBLK) {
  __shared__ int p[512];
  const int t = threadIdx.x;
  const bool isS = blockIdx.x >= NB;
  const int b = isS ? blockIdx.x - NB : blockIdx.x;
  const int* cnt = isS ? cntS : cntD;
  int* offL = isS ? offLS : offLD;
  int own = (t < NBLK) ? cnt[b * NBLK + t] : 0;
  p[t] = own;
  __syncthreads();
  for (int off = 1; off < 512; off <<= 1) {
    int x = (t >= off) ? p[t - off] : 0;
    __syncthreads();
    p[t] += x;
    __syncthreads();
  }
  if (t < NBLK) offL[b * NBLK + t] = p[t] - own;
  if (t == 511) (isS ? totS : totD)[b] = p[511];
}

// ==== scan2: exclusive scan of bucket totals -> bucket_start (1 block) ====
__global__ __launch_bounds__(512) void scan2_kernel(
    const int* __restrict__ totD, const int* __restrict__ totS,
    int* __restrict__ bktD, int* __restrict__ bktS,
    int* __restrict__ row_st, int NB, int N, int E) {
  __shared__ int p[512];
  const int t = threadIdx.x;
  int own = (t < NB) ? totD[t] : 0;
  p[t] = own;
  __syncthreads();
  for (int off = 1; off < 512; off <<= 1) {
    int x = (t >= off) ? p[t - off] : 0;
    __syncthreads();
    p[t] += x;
    __syncthreads();
  }
  if (t < NB) bktD[t] = p[t] - own;
  __syncthreads();
  int own2 = (t < NB) ? totS[t] : 0;
  p[t] = own2;
  __syncthreads();
  for (int off = 1; off < 512; off <<= 1) {
    int x = (t >= off) ? p[t - off] : 0;
    __syncthreads();
    p[t] += x;
    __syncthreads();
  }
  if (t < NB) bktS[t] = p[t] - own2;
  if (t == 0) {
    bktD[NB] = E;
    bktS[NB] = E;
    row_st[N] = E;
  }
}

// ===== passB: reuse passA histograms; single edge read; LDS sort+copyout ==
__global__ __launch_bounds__(256) void passB_kernel(
    const int* __restrict__ src, const int* __restrict__ dst,
    const int* __restrict__ cntD, const int* __restrict__ cntS,
    const int* __restrict__ offLD, const int* __restrict__ offLS,
    const int* __restrict__ bkt_stD, const int* __restrict__ bkt_stS,
    unsigned int* __restrict__ packedD, unsigned char* __restrict__ srcS,
    int NB, int NBLK, int E) {
  __shared__ unsigned int sD[CHUNK];
  __shared__ unsigned short bD_[CHUNK];
  __shared__ unsigned char sS_[CHUNK];
  __shared__ unsigned short bS_[CHUNK];
  __shared__ int hD[512], lD[512], hS[512], lS[512];
  const int t = threadIdx.x;
  const int blk = blockIdx.x;
  const int base = blk * CHUNK;
  const int end = min(base + CHUNK, E);
  const int cnt = end - base;
  hD[t] = (t < NB) ? cntD[t * NBLK + blk] : 0;
  hD[t + 256] = (t + 256 < NB) ? cntD[(t + 256) * NBLK + blk] : 0;
  hS[t] = (t < NB) ? cntS[t * NBLK + blk] : 0;
  hS[t + 256] = (t + 256 < NB) ? cntS[(t + 256) * NBLK + blk] : 0;
  __syncthreads();
  int oD0 = hD[t], oD1 = hD[t + 256], oS0 = hS[t], oS1 = hS[t + 256];
  for (int off = 1; off < 512; off <<= 1) {
    int xd0 = (t >= off) ? hD[t - off] : 0;
    int xd1 = (t + 256 >= off) ? hD[t + 256 - off] : 0;
    int xs0 = (t >= off) ? hS[t - off] : 0;
    int xs1 = (t + 256 >= off) ? hS[t + 256 - off] : 0;
    __syncthreads();
    hD[t] += xd0; hD[t + 256] += xd1;
    hS[t] += xs0; hS[t + 256] += xs1;
    __syncthreads();
  }
  lD[t] = hD[t] - oD0; lD[t + 256] = hD[t + 256] - oD1;
  lS[t] = hS[t] - oS0; lS[t + 256] = hS[t + 256] - oS1;
  __syncthreads();
  hD[t] = lD[t]; hD[t + 256] = lD[t + 256];
  hS[t] = lS[t]; hS[t + 256] = lS[t + 256];
  __syncthreads();
  const int nv = cnt >> 2;
  const int4* d4p = reinterpret_cast<const int4*>(dst + base);
  const int4* s4p = reinterpret_cast<const int4*>(src + base);
  for (int q = t; q < nv; q += 256) {
    int4 d4 = d4p[q];
    int4 s4 = s4p[q];
#pragma unroll
    for (int k = 0; k < 4; ++k) {
      const int d = (&d4.x)[k];
      const int s = (&s4.x)[k];
      const int bD = d >> 8;
      const int pD = atomicAdd(&hD[bD], 1);
      sD[pD] = ((unsigned int)(d & 255) << 24) | (unsigned int)s;
      bD_[pD] = (unsigned short)bD;
      const int bS = s >> 8;
      const int pS = atomicAdd(&hS[bS], 1);
      sS_[pS] = (unsigned char)(s & 255);
      bS_[pS] = (unsigned short)bS;
    }
  }
  for (int i = (nv << 2) + t; i < cnt; i += 256) {
    const int d = dst[base + i];
    const int s = src[base + i];
    const int bD = d >> 8;
    const int pD = atomicAdd(&hD[bD], 1);
    sD[pD] = ((unsigned int)(d & 255) << 24) | (unsigned int)s;
    bD_[pD] = (unsigned short)bD;
    const int bS = s >> 8;
    const int pS = atomicAdd(&hS[bS], 1);
    sS_[pS] = (unsigned char)(s & 255);
    bS_[pS] = (unsigned short)bS;
  }
  __syncthreads();
  for (int i = t; i < cnt; i += 256) {
    const int bD = bD_[i];
    packedD[bkt_stD[bD] + offLD[bD * NBLK + blk] + (i - lD[bD])] = sD[i];
    const int bS = bS_[i];
    srcS[bkt_stS[bS] + offLS[bS * NBLK + blk] + (i - lS[bS])] = sS_[i];
  }
}

// ===== passC: per-bucket local CSR (row_st, norm_i, sorted edge_src) ======
__global__ __launch_bounds__(256) void passC_kernel(
    const unsigned int* __restrict__ packed, const int* __restrict__ bucket_start,
    int* __restrict__ row_st, float* __restrict__ ni,
    int* __restrict__ edge_src, int N) {
  __shared__ int cnt[NPB];
  __shared__ int cur[NPB];
  __shared__ int tmp[NPB];
  const int b = blockIdx.x;
  const int t = threadIdx.x;
  const int v0 = b * NPB;
  const int bs = bucket_start[b];
  const int be = bucket_start[b + 1];
  cnt[t] = 0;
  __syncthreads();
  const int a0 = bs + ((4 - (bs & 3)) & 3);
  const int a1 = a0 + (((be - a0) >> 2) << 2);
  for (int i = bs + t; i < min(a0, be); i += 256)
    atomicAdd(&cnt[packed[i] >> 24], 1);
  const uint4* p4 = reinterpret_cast<const uint4*>(packed + a0);
  const int nv = (a1 - a0) >> 2;
  for (int q = t; q < nv; q += 256) {
    uint4 p = p4[q];
    atomicAdd(&cnt[p.x >> 24], 1); atomicAdd(&cnt[p.y >> 24], 1);
    atomicAdd(&cnt[p.z >> 24], 1); atomicAdd(&cnt[p.w >> 24], 1);
  }
  for (int i = max(a1, bs) + t; i < be; i += 256)
    atomicAdd(&cnt[packed[i] >> 24], 1);
  __syncthreads();
  int own = cnt[t];
  tmp[t] = own;
  __syncthreads();
  for (int off = 1; off < NPB; off <<= 1) {
    int x = (t >= off) ? tmp[t - off] : 0;
    __syncthreads();
    tmp[t] += x;
    __syncthreads();
  }
  const int pref = tmp[t] - own;
  if (v0 + t < N) {
    row_st[v0 + t] = bs + pref;
    ni[v0 + t] = rsqrtf(fmaxf((float)own, 1.0f));
  }
  cur[t] = bs + pref;
  __syncthreads();
  for (int i = bs + t; i < min(a0, be); i += 256) {
    unsigned int p = packed[i];
    int pos = atomicAdd(&cur[p >> 24], 1);
    edge_src[pos] = (int)(p & 0xFFFFFFu);
  }
  for (int q = t; q < nv; q += 256) {
    uint4 p = p4[q];
#pragma unroll
    for (int k = 0; k < 4; ++k) {
      unsigned int pv = (&p.x)[k];
      int pos = atomicAdd(&cur[pv >> 24], 1);
      edge_src[pos] = (int)(pv & 0xFFFFFFu);
    }
  }
  for (int i = max(a1, bs) + t; i < be; i += 256) {
    unsigned int p = packed[i];
    int pos = atomicAdd(&cur[p >> 24], 1);
    edge_src[pos] = (int)(p & 0xFFFFFFu);
  }
}

// ========= passD: per-src-bucket count -> norm_o (no global atomics) ======
__global__ __launch_bounds__(256) void passD_kernel(
    const unsigned char* __restrict__ srcS, const int* __restrict__ bkt_stS,
    float* __restrict__ no, int N) {
  __shared__ int cnt[NPB];
  const int b = blockIdx.x;
  const int t = threadIdx.x;
  cnt[t] = 0;
  __syncthreads();
  const int bs = bkt_stS[b];
  const int be = bkt_stS[b + 1];
  for (int i = bs + t; i < be; i += 256)
    atomicAdd(&cnt[srcS[i]], 1);
  __syncthreads();
  const int v = b * NPB + t;
  if (v < N) no[v] = rsqrtf(fmaxf((float)cnt[t], 1.0f));
}

// ===================== weight transpose + f16 convert =====================
__global__ void wconv_kernel(const float* __restrict__ W, unsigned short* __restrict__ Wt,
                             int K, int C) {
  int i = blockIdx.x * blockDim.x + threadIdx.x;
  if (i < K * C) {
    int k = i / C, c = i - k * C;
    Wt[c * K + k] = f2h(W[i]);
  }
}

// ============= feats f32 -> f16 with norm_o fold: out = no[r]*F[r][c] =====
__global__ __launch_bounds__(256) void featconv_kernel(const float* __restrict__ F,
                                                       const float* __restrict__ no,
                                                       unsigned short* __restrict__ out, int N) {
  int row = blockIdx.x * 8 + (threadIdx.x >> 5);
  if (row >= N) return;
  int c = (threadIdx.x & 31) * 4;
  float4 v = *reinterpret_cast<const float4*>(F + (size_t)row * 128 + c);
  float nof = no[row];
  uint2 p = {pk2h(v.x * nof, v.y * nof), pk2h(v.z * nof, v.w * nof)};
  *reinterpret_cast<uint2*>(out + (size_t)row * 128 + c) = p;
}

// ===== column-sliced gather (128 cols, 8 slices x 16 cols) ================
// Per slice pass the live h-slice is 3.2 MB < 4 MB/XCD L2 -> L2-resident.
// Wave = 8 groups x 8 lanes; group = edge slot, lane = col pair.
// Each wave handles 8 nodes sequentially; grid = gblocks * 8 (slice-major).
__global__ __launch_bounds__(256) void gather_slice(
    const unsigned short* __restrict__ hH, const int* __restrict__ row_start,
    const int* __restrict__ edge_src, const float* __restrict__ ni,
    unsigned short* __restrict__ aggH, int N, int gblocks) {
  const int slice = blockIdx.x / gblocks;      // 0..7
  const int nb = blockIdx.x - slice * gblocks;
  const int w = threadIdx.x >> 6;
  const int l = threadIdx.x & 63;
  const int grp = l >> 3;   // edge slot 0..7
  const int lane = l & 7;   // col pair 0..7
  const int co = slice * 16 + lane * 2;
  const int vbase = nb * 32 + w * 8;
  const __half2 zz = __float2half2_rn(0.f);
#pragma unroll 1
  for (int k = 0; k < 8; ++k) {
    const int v = vbase + k;
    if (v >= N) break;
    const int s = row_start[v];
    const int e = row_start[v + 1];
    __half2 acc = zz;
    for (int j = s + grp; j < e; j += 8)
      acc = __hadd2(acc, u2h2(*reinterpret_cast<const unsigned int*>(
                        hH + (size_t)edge_src[j] * 128 + co)));
    float a0 = __low2float(acc), a1 = __high2float(acc);
    a0 += __shfl_xor(a0, 8);  a1 += __shfl_xor(a1, 8);
    a0 += __shfl_xor(a0, 16); a1 += __shfl_xor(a1, 16);
    a0 += __shfl_xor(a0, 32); a1 += __shfl_xor(a1, 32);
    if (grp == 0) {
      const float niv = ni[v];
      *reinterpret_cast<unsigned int*>(aggH + (size_t)v * 128 + co) =
          pk2h(a0 * niv, a1 * niv);
    }
  }
}

// ===== final sliced gather (64 cols, 4 slices): out = ni*sum z + b2 =======
__global__ __launch_bounds__(256) void gather_out_slice(
    const unsigned short* __restrict__ zH, const int* __restrict__ row_start,
    const int* __restrict__ edge_src, const float* __restrict__ ni,
    const float* __restrict__ bias, float* __restrict__ out, int N, int gblocks) {
  const int slice = blockIdx.x / gblocks;      // 0..3
  const int nb = blockIdx.x - slice * gblocks;
  const int w = threadIdx.x >> 6;
  const int l = threadIdx.x & 63;
  const int grp = l >> 3;
  const int lane = l & 7;
  const int co = slice * 16 + lane * 2;
  const int vbase = nb * 32 + w * 8;
  const __half2 zz = __float2half2_rn(0.f);
#pragma unroll 1
  for (int k = 0; k < 8; ++k) {
    const int v = vbase + k;
    if (v >= N) break;
    const int s = row_start[v];
    const int e = row_start[v + 1];
    __half2 acc = zz;
    for (int j = s + grp; j < e; j += 8)
      acc = __hadd2(acc, u2h2(*reinterpret_cast<const unsigned int*>(
                        zH + (size_t)edge_src[j] * 64 + co)));
    float a0 = __low2float(acc), a1 = __high2float(acc);
    a0 += __shfl_xor(a0, 8);  a1 += __shfl_xor(a1, 8);
    a0 += __shfl_xor(a0, 16); a1 += __shfl_xor(a1, 16);
    a0 += __shfl_xor(a0, 32); a1 += __shfl_xor(a1, 32);
    if (grp == 0) {
      const float niv = ni[v];
      float2 bb = *reinterpret_cast<const float2*>(bias + co);
      float2 o = {a0 * niv + bb.x, a1 * niv + bb.y};
      *reinterpret_cast<float2*>(out + (size_t)v * 64 + co) = o;
    }
  }
}

// ====== MFMA matmul [N,128]x[128,128] + bias + LN + ReLU + no-fold (f16) ==
__global__ __launch_bounds__(256) void mm_mfma_ln(
    const unsigned short* __restrict__ A, const unsigned short* __restrict__ Wt,
    const float* __restrict__ b, const float* __restrict__ g,
    const float* __restrict__ be, const float* __restrict__ no,
    unsigned short* __restrict__ out, int N) {
  __shared__ float sS[2][2][16];
  __shared__ float sQ[2][2][16];
  __shared__ float sNo[32];
  const int rbase = blockIdx.x * 32;
  const int w = threadIdx.x >> 6;
  const int l = threadIdx.x & 63;
  const int rt = w & 1, ch = w >> 1;
  if (threadIdx.x < 32) sNo[threadIdx.x] = no[min(rbase + (int)threadIdx.x, N - 1)];
  const int arow = min(rbase + rt * 16 + (l & 15), N - 1);
  const int kof = (l >> 4) * 8;

  f16x8 af[4];
  const unsigned short* ap = A + (size_t)arow * 128 + kof;
#pragma unroll
  for (int kk = 0; kk < 4; ++kk)
    af[kk] = *reinterpret_cast<const f16x8*>(ap + kk * 32);

  f32x4 acc[4] = {};
#pragma unroll
  for (int ct = 0; ct < 4; ++ct) {
    const int ccol = ch * 64 + ct * 16 + (l & 15);
    const unsigned short* bp = Wt + (size_t)ccol * 128 + kof;
#pragma unroll
    for (int kk = 0; kk < 4; ++kk) {
      f16x8 bfr = *reinterpret_cast<const f16x8*>(bp + kk * 32);
      acc[ct] = __builtin_amdgcn_mfma_f32_16x16x32_f16(af[kk], bfr, acc[ct], 0, 0, 0);
    }
  }

  float s[4] = {0.f, 0.f, 0.f, 0.f}, q[4] = {0.f, 0.f, 0.f, 0.f};
#pragma unroll
  for (int ct = 0; ct < 4; ++ct) {
    const float bc = b[ch * 64 + ct * 16 + (l & 15)];
#pragma unroll
    for (int j = 0; j < 4; ++j) {
      float v = acc[ct][j] + bc;
      acc[ct][j] = v;
      s[j] += v;
      q[j] += v * v;
    }
  }
#pragma unroll
  for (int j = 0; j < 4; ++j) {
#pragma unroll
    for (int off = 1; off < 16; off <<= 1) {
      s[j] += __shfl_xor(s[j], off);
      q[j] += __shfl_xor(q[j], off);
    }
  }
  const int grp = l >> 4;
  if ((l & 15) == 0) {
#pragma unroll
    for (int j = 0; j < 4; ++j) {
      sS[rt][ch][grp * 4 + j] = s[j];
      sQ[rt][ch][grp * 4 + j] = q[j];
    }
  }
  __syncthreads();

#pragma unroll
  for (int j = 0; j < 4; ++j) {
    const int r = grp * 4 + j;
    const int row = rbase + rt * 16 + r;
    float S = sS[rt][0][r] + sS[rt][1][r];
    float Q = sQ[rt][0][r] + sQ[rt][1][r];
    float mu = S * (1.f / 128.f);
    float rstd = rsqrtf(fmaxf(Q * (1.f / 128.f) - mu * mu, 0.f) + LN_EPS);
    float nof = sNo[rt * 16 + r];
    if (row < N) {
#pragma unroll
      for (int ct = 0; ct < 4; ++ct) {
        const int ccol = ch * 64 + ct * 16 + (l & 15);
        float y = (acc[ct][j] - mu) * rstd * g[ccol] + be[ccol];
        y = fmaxf(y, 0.f) * nof;
        out[(size_t)row * 128 + ccol] = f2h(y);
      }
    }
  }
}

// ==== fused layer-1: mm+bias+LN+ReLU+no-fold -> LDS tile -> z = h'@W2 =====
// Writes ONLY zH [N,64] (h' never hits global memory).
__global__ __launch_bounds__(256) void mm_ln_z(
    const unsigned short* __restrict__ A, const unsigned short* __restrict__ Wt,
    const float* __restrict__ b, const float* __restrict__ g,
    const float* __restrict__ be, const float* __restrict__ no,
    const unsigned short* __restrict__ Wt2, unsigned short* __restrict__ zH, int N) {
  __shared__ float sS[2][2][16];
  __shared__ float sQ[2][2][16];
  __shared__ float sNo[32];
  __shared__ unsigned short ht[32][136];  // +8 pad: stage-2 reads 2-way-free
  const int rbase = blockIdx.x * 32;
  const int w = threadIdx.x >> 6;
  const int l = threadIdx.x & 63;
  const int rt = w & 1, ch = w >> 1;
  if (threadIdx.x < 32) sNo[threadIdx.x] = no[min(rbase + (int)threadIdx.x, N - 1)];
  const int arow = min(rbase + rt * 16 + (l & 15), N - 1);
  const int kof = (l >> 4) * 8;

  f16x8 af[4];
  const unsigned short* ap = A + (size_t)arow * 128 + kof;
#pragma unroll
  for (int kk = 0; kk < 4; ++kk)
    af[kk] = *reinterpret_cast<const f16x8*>(ap + kk * 32);

  f32x4 acc[4] = {};
#pragma unroll
  for (int ct = 0; ct < 4; ++ct) {
    const int ccol = ch * 64 + ct * 16 + (l & 15);
    const unsigned short* bp = Wt + (size_t)ccol * 128 + kof;
#pragma unroll
    for (int kk = 0; kk < 4; ++kk) {
      f16x8 bfr = *reinterpret_cast<const f16x8*>(bp + kk * 32);
      acc[ct] = __builtin_amdgcn_mfma_f32_16x16x32_f16(af[kk], bfr, acc[ct], 0, 0, 0);
    }
  }

  float s[4] = {0.f, 0.f, 0.f, 0.f}, q[4] = {0.f, 0.f, 0.f, 0.f};
#pragma unroll
  for (int ct = 0; ct < 4; ++ct) {
    const float bc = b[ch * 64 + ct * 16 + (l & 15)];
#pragma unroll
    for (int j = 0; j < 4; ++j) {
      float v = acc[ct][j] + bc;
      acc[ct][j] = v;
      s[j] += v;
      q[j] += v * v;
    }
  }
#pragma unroll
  for (int j = 0; j < 4; ++j) {
#pragma unroll
    for (int off = 1; off < 16; off <<= 1) {
      s[j] += __shfl_xor(s[j], off);
      q[j] += __shfl_xor(q[j], off);
    }
  }
  const int grp = l >> 4;
  if ((l & 15) == 0) {
#pragma unroll
    for (int j = 0; j < 4; ++j) {
      sS[rt][ch][grp * 4 + j] = s[j];
      sQ[rt][ch][grp * 4 + j] = q[j];
    }
  }
  __syncthreads();

#pragma unroll
  for (int j = 0; j < 4; ++j) {
    const int r = grp * 4 + j;
    float S = sS[rt][0][r] + sS[rt][1][r];
    float Q = sQ[rt][0][r] + sQ[rt][1][r];
    float mu = S * (1.f / 128.f);
    float rstd = rsqrtf(fmaxf(Q * (1.f / 128.f) - mu * mu, 0.f) + LN_EPS);
    float nof = sNo[rt * 16 + r];
#pragma unroll
    for (int ct = 0; ct < 4; ++ct) {
      const int ccol = ch * 64 + ct * 16 + (l & 15);
      float y = (acc[ct][j] - mu) * rstd * g[ccol] + be[ccol];
      y = fmaxf(y, 0.f) * nof;
      ht[rt * 16 + r][ccol] = f2h(y);
    }
  }
  __syncthreads();

  // stage 2: z-tile = ht @ W2 (128 -> 64). wave w: rows rt*16.., cols ch*32..
  f16x8 af2[4];
#pragma unroll
  for (int kk = 0; kk < 4; ++kk)
    af2[kk] = *reinterpret_cast<const f16x8*>(&ht[rt * 16 + (l & 15)][kof + kk * 32]);

  f32x4 acc2[2] = {};
#pragma unroll
  for (int ct = 0; ct < 2; ++ct) {
    const int ccol = ch * 32 + ct * 16 + (l & 15);
    const unsigned short* bp = Wt2 + (size_t)ccol * 128 + kof;
#pragma unroll
    for (int kk = 0; kk < 4; ++kk) {
      f16x8 bfr = *reinterpret_cast<const f16x8*>(bp + kk * 32);
      acc2[ct] = __builtin_amdgcn_mfma_f32_16x16x32_f16(af2[kk], bfr, acc2[ct], 0, 0, 0);
    }
  }
#pragma unroll
  for (int ct = 0; ct < 2; ++ct) {
    const int ccol = ch * 32 + ct * 16 + (l & 15);
#pragma unroll
    for (int j = 0; j < 4; ++j) {
      const int row = rbase + rt * 16 + grp * 4 + j;
      if (row < N) zH[(size_t)row * 64 + ccol] = f2h(acc2[ct][j]);
    }
  }
}

extern "C" void kernel_launch(void* const* d_in, const int* in_sizes, int n_in,
                              void* d_out, int out_size, void* d_ws, size_t ws_size,
                              hipStream_t stream) {
  const float* feats = (const float*)d_in[0];
  const int*   src   = (const int*)d_in[1];
  const int*   dst   = (const int*)d_in[2];
  const float* W0    = (const float*)d_in[3];
  const float* b0    = (const float*)d_in[4];
  const float* g0    = (const float*)d_in[5];
  const float* be0   = (const float*)d_in[6];
  const float* W1    = (const float*)d_in[7];
  const float* b1    = (const float*)d_in[8];
  const float* g1    = (const float*)d_in[9];
  const float* be1   = (const float*)d_in[10];
  const float* W2    = (const float*)d_in[11];
  const float* b2    = (const float*)d_in[12];
  float* out = (float*)d_out;

  const int n = in_sizes[0] / 128;  // 100000
  const int e = in_sizes[1];        // 1600000
  const int NB = (n + NPB - 1) / NPB;        // 391 buckets
  const int NBLK = (e + CHUNK - 1) / CHUNK;  // 391 chunks

  float* ws = (float*)d_ws;
  auto pad4 = [](size_t x) { return (x + 3) & ~(size_t)3; };
  size_t o = 0;
  float* norm_o  = ws + o; o = pad4(o + n);
  float* norm_i  = ws + o; o = pad4(o + n);
  int*   cntD    = (int*)(ws + o); o = pad4(o + (size_t)NB * NBLK);
  int*   cntS    = (int*)(ws + o); o = pad4(o + (size_t)NB * NBLK);
  int*   offLD   = (int*)(ws + o); o = pad4(o + (size_t)NB * NBLK);
  int*   offLS   = (int*)(ws + o); o = pad4(o + (size_t)NB * NBLK);
  int*   totD    = (int*)(ws + o); o = pad4(o + NB);
  int*   totS    = (int*)(ws + o); o = pad4(o + NB);
  int*   bkt_stD = (int*)(ws + o); o = pad4(o + NB + 1);
  int*   bkt_stS = (int*)(ws + o); o = pad4(o + NB + 1);
  int*   row_st  = (int*)(ws + o); o = pad4(o + n + 1);
  unsigned int*  packedD = (unsigned int*)(ws + o);  o = pad4(o + (size_t)e);
  unsigned char* srcS    = (unsigned char*)(ws + o); o = pad4(o + (size_t)(e + 3) / 4);
  int*   edg_src = (int*)(ws + o); o = pad4(o + (size_t)e);
  unsigned short* featH = (unsigned short*)(ws + o); o = pad4(o + (size_t)n * 64);  // also hH
  unsigned short* aggH  = (unsigned short*)(ws + o); o = pad4(o + (size_t)n * 64);
  unsigned short* zH    = (unsigned short*)(ws + o); o = pad4(o + (size_t)n * 32);
  unsigned short* Wt0   = (unsigned short*)(ws + o); o = pad4(o + 128 * 128 / 2);
  unsigned short* Wt1   = (unsigned short*)(ws + o); o = pad4(o + 128 * 128 / 2);
  unsigned short* Wt2   = (unsigned short*)(ws + o); o = pad4(o + 128 * 64 / 2);
  unsigned short* hH = featH;  // featH dead after layer-0 gather

  // ---- CSR build: atomic-free radix partition ----
  passA_kernel<<<NBLK, 256, 2 * NB * sizeof(int), stream>>>(src, dst, cntD, cntS, NB, NBLK, e);
  scan1_kernel<<<2 * NB, 512, 0, stream>>>(cntD, cntS, offLD, offLS, totD, totS, NB, NBLK);
  scan2_kernel<<<1, 512, 0, stream>>>(totD, totS, bkt_stD, bkt_stS, row_st, NB, n, e);
  passB_kernel<<<NBLK, 256, 0, stream>>>(src, dst, cntD, cntS, offLD, offLS, bkt_stD, bkt_stS,
                                         packedD, srcS, NB, NBLK, e);
  passC_kernel<<<NB, 256, 0, stream>>>(packedD, bkt_stD, row_st, norm_i, edg_src, n);
  passD_kernel<<<NB, 256, 0, stream>>>(srcS, bkt_stS, norm_o, n);

  // ---- weights -> f16 transposed; feats -> f16 with no-fold ----
  wconv_kernel<<<(128 * 128 + 255) / 256, 256, 0, stream>>>(W0, Wt0, 128, 128);
  wconv_kernel<<<(128 * 128 + 255) / 256, 256, 0, stream>>>(W1, Wt1, 128, 128);
  wconv_kernel<<<(128 * 64 + 255) / 256, 256, 0, stream>>>(W2, Wt2, 128, 64);
  featconv_kernel<<<(n + 7) / 8, 256, 0, stream>>>(feats, norm_o, featH, n);

  const int g32 = (n + 31) / 32;          // node blocks (32 nodes each)
  const int mblocks = (n + 31) / 32;

  // layer 0
  gather_slice<<<g32 * 8, 256, 0, stream>>>(featH, row_st, edg_src, norm_i, aggH, n, g32);
  mm_mfma_ln<<<mblocks, 256, 0, stream>>>(aggH, Wt0, b0, g0, be0, norm_o, hH, n);
  // layer 1 (fused with commuted final matmul)
  gather_slice<<<g32 * 8, 256, 0, stream>>>(hH, row_st, edg_src, norm_i, aggH, n, g32);
  mm_ln_z<<<mblocks, 256, 0, stream>>>(aggH, Wt1, b1, g1, be1, norm_o, Wt2, zH, n);
  // final: 64-wide sliced gather + bias -> f32 out
  gather_out_slice<<<g32 * 4, 256, 0, stream>>>(zH, row_st, edg_src, norm_i, b2, out, n, g32);
}

// Round 11
// 374.642 us; speedup vs baseline: 2.3581x; 2.3581x over previous
//
#include <hip/hip_runtime.h>
#include <hip/hip_fp16.h>

constexpr float LN_EPS = 1e-5f;

typedef _Float16 f16x8 __attribute__((ext_vector_type(8)));
typedef float f32x4 __attribute__((ext_vector_type(4)));

__device__ __forceinline__ unsigned short f2h(float f) {
  return __half_as_ushort(__float2half_rn(f));
}
__device__ __forceinline__ unsigned int pk2h(float x, float y) {
  return (unsigned int)f2h(x) | ((unsigned int)f2h(y) << 16);
}
__device__ __forceinline__ __half2 u2h2(unsigned int u) {
  return *reinterpret_cast<__half2*>(&u);
}

#define NPB 256    // nodes per bucket (bucket = node >> 8)
#define CHUNK 4096 // edges per partition block

// ======== passA: per-chunk LDS histograms (dst-bucket & src-bucket) =======
__global__ __launch_bounds__(256) void passA_kernel(
    const int* __restrict__ src, const int* __restrict__ dst,
    int* __restrict__ cntD, int* __restrict__ cntS, int NB, int NBLK, int E) {
  extern __shared__ int sh[];  // 2*NB
  for (int j = threadIdx.x; j < 2 * NB; j += 256) sh[j] = 0;
  __syncthreads();
  const int blk = blockIdx.x;
  const int base = blk * CHUNK;
  const int end = min(base + CHUNK, E);
  const int cnt = end - base;
  const int nv = cnt >> 2;
  const int4* d4p = reinterpret_cast<const int4*>(dst + base);
  const int4* s4p = reinterpret_cast<const int4*>(src + base);
  for (int q = threadIdx.x; q < nv; q += 256) {
    int4 d4 = d4p[q];
    int4 s4 = s4p[q];
    atomicAdd(&sh[d4.x >> 8], 1); atomicAdd(&sh[d4.y >> 8], 1);
    atomicAdd(&sh[d4.z >> 8], 1); atomicAdd(&sh[d4.w >> 8], 1);
    atomicAdd(&sh[NB + (s4.x >> 8)], 1); atomicAdd(&sh[NB + (s4.y >> 8)], 1);
    atomicAdd(&sh[NB + (s4.z >> 8)], 1); atomicAdd(&sh[NB + (s4.w >> 8)], 1);
  }
  for (int i = (nv << 2) + threadIdx.x; i < cnt; i += 256) {
    atomicAdd(&sh[dst[base + i] >> 8], 1);
    atomicAdd(&sh[NB + (src[base + i] >> 8)], 1);
  }
  __syncthreads();
  for (int j = threadIdx.x; j < NB; j += 256) {
    cntD[j * NBLK + blk] = sh[j];
    cntS[j * NBLK + blk] = sh[NB + j];
  }
}

// ==== scan1: per-bucket exclusive scan over blocks (grid = 2*NB blocks) ===
__global__ __launch_bounds__(512) void scan1_kernel(
    const int* __restrict__ cntD, const int* __restrict__ cntS,
    int* __restrict__ offLD, int* __restrict__ offLS,
    int* __restrict__ totD, int* __restrict__ totS, int NB, int NBLK) {
  __shared__ int p[512];
  const int t = threadIdx.x;
  const bool isS = blockIdx.x >= NB;
  const int b = isS ? blockIdx.x - NB : blockIdx.x;
  const int* cnt = isS ? cntS : cntD;
  int* offL = isS ? offLS : offLD;
  int own = (t < NBLK) ? cnt[b * NBLK + t] : 0;
  p[t] = own;
  __syncthreads();
  for (int off = 1; off < 512; off <<= 1) {
    int x = (t >= off) ? p[t - off] : 0;
    __syncthreads();
    p[t] += x;
    __syncthreads();
  }
  if (t < NBLK) offL[b * NBLK + t] = p[t] - own;
  if (t == 511) (isS ? totS : totD)[b] = p[511];
}

// ==== scan2: exclusive scan of bucket totals -> bucket_start (1 block) ====
__global__ __launch_bounds__(512) void scan2_kernel(
    const int* __restrict__ totD, const int* __restrict__ totS,
    int* __restrict__ bktD, int* __restrict__ bktS,
    int* __restrict__ row_st, int NB, int N, int E) {
  __shared__ int p[512];
  const int t = threadIdx.x;
  int own = (t < NB) ? totD[t] : 0;
  p[t] = own;
  __syncthreads();
  for (int off = 1; off < 512; off <<= 1) {
    int x = (t >= off) ? p[t - off] : 0;
    __syncthreads();
    p[t] += x;
    __syncthreads();
  }
  if (t < NB) bktD[t] = p[t] - own;
  __syncthreads();
  int own2 = (t < NB) ? totS[t] : 0;
  p[t] = own2;
  __syncthreads();
  for (int off = 1; off < 512; off <<= 1) {
    int x = (t >= off) ? p[t - off] : 0;
    __syncthreads();
    p[t] += x;
    __syncthreads();
  }
  if (t < NB) bktS[t] = p[t] - own2;
  if (t == 0) {
    bktD[NB] = E;
    bktS[NB] = E;
    row_st[N] = E;
  }
}

// ===== passB: reuse passA histograms; single edge read; LDS sort+copyout ==
__global__ __launch_bounds__(256) void passB_kernel(
    const int* __restrict__ src, const int* __restrict__ dst,
    const int* __restrict__ cntD, const int* __restrict__ cntS,
    const int* __restrict__ offLD, const int* __restrict__ offLS,
    const int* __restrict__ bkt_stD, const int* __restrict__ bkt_stS,
    unsigned int* __restrict__ packedD, unsigned char* __restrict__ srcS,
    int NB, int NBLK, int E) {
  __shared__ unsigned int sD[CHUNK];
  __shared__ unsigned short bD_[CHUNK];
  __shared__ unsigned char sS_[CHUNK];
  __shared__ unsigned short bS_[CHUNK];
  __shared__ int hD[512], lD[512], hS[512], lS[512];
  const int t = threadIdx.x;
  const int blk = blockIdx.x;
  const int base = blk * CHUNK;
  const int end = min(base + CHUNK, E);
  const int cnt = end - base;
  hD[t] = (t < NB) ? cntD[t * NBLK + blk] : 0;
  hD[t + 256] = (t + 256 < NB) ? cntD[(t + 256) * NBLK + blk] : 0;
  hS[t] = (t < NB) ? cntS[t * NBLK + blk] : 0;
  hS[t + 256] = (t + 256 < NB) ? cntS[(t + 256) * NBLK + blk] : 0;
  __syncthreads();
  int oD0 = hD[t], oD1 = hD[t + 256], oS0 = hS[t], oS1 = hS[t + 256];
  for (int off = 1; off < 512; off <<= 1) {
    int xd0 = (t >= off) ? hD[t - off] : 0;
    int xd1 = (t + 256 >= off) ? hD[t + 256 - off] : 0;
    int xs0 = (t >= off) ? hS[t - off] : 0;
    int xs1 = (t + 256 >= off) ? hS[t + 256 - off] : 0;
    __syncthreads();
    hD[t] += xd0; hD[t + 256] += xd1;
    hS[t] += xs0; hS[t + 256] += xs1;
    __syncthreads();
  }
  lD[t] = hD[t] - oD0; lD[t + 256] = hD[t + 256] - oD1;
  lS[t] = hS[t] - oS0; lS[t + 256] = hS[t + 256] - oS1;
  __syncthreads();
  hD[t] = lD[t]; hD[t + 256] = lD[t + 256];
  hS[t] = lS[t]; hS[t + 256] = lS[t + 256];
  __syncthreads();
  const int nv = cnt >> 2;
  const int4* d4p = reinterpret_cast<const int4*>(dst + base);
  const int4* s4p = reinterpret_cast<const int4*>(src + base);
  for (int q = t; q < nv; q += 256) {
    int4 d4 = d4p[q];
    int4 s4 = s4p[q];
#pragma unroll
    for (int k = 0; k < 4; ++k) {
      const int d = (&d4.x)[k];
      const int s = (&s4.x)[k];
      const int bD = d >> 8;
      const int pD = atomicAdd(&hD[bD], 1);
      sD[pD] = ((unsigned int)(d & 255) << 24) | (unsigned int)s;
      bD_[pD] = (unsigned short)bD;
      const int bS = s >> 8;
      const int pS = atomicAdd(&hS[bS], 1);
      sS_[pS] = (unsigned char)(s & 255);
      bS_[pS] = (unsigned short)bS;
    }
  }
  for (int i = (nv << 2) + t; i < cnt; i += 256) {
    const int d = dst[base + i];
    const int s = src[base + i];
    const int bD = d >> 8;
    const int pD = atomicAdd(&hD[bD], 1);
    sD[pD] = ((unsigned int)(d & 255) << 24) | (unsigned int)s;
    bD_[pD] = (unsigned short)bD;
    const int bS = s >> 8;
    const int pS = atomicAdd(&hS[bS], 1);
    sS_[pS] = (unsigned char)(s & 255);
    bS_[pS] = (unsigned short)bS;
  }
  __syncthreads();
  for (int i = t; i < cnt; i += 256) {
    const int bD = bD_[i];
    packedD[bkt_stD[bD] + offLD[bD * NBLK + blk] + (i - lD[bD])] = sD[i];
    const int bS = bS_[i];
    srcS[bkt_stS[bS] + offLS[bS * NBLK + blk] + (i - lS[bS])] = sS_[i];
  }
}

// ===== passC: per-bucket local CSR (row_st, norm_i, sorted edge_src) ======
__global__ __launch_bounds__(256) void passC_kernel(
    const unsigned int* __restrict__ packed, const int* __restrict__ bucket_start,
    int* __restrict__ row_st, float* __restrict__ ni,
    int* __restrict__ edge_src, int N) {
  __shared__ int cnt[NPB];
  __shared__ int cur[NPB];
  __shared__ int tmp[NPB];
  const int b = blockIdx.x;
  const int t = threadIdx.x;
  const int v0 = b * NPB;
  const int bs = bucket_start[b];
  const int be = bucket_start[b + 1];
  cnt[t] = 0;
  __syncthreads();
  const int a0 = bs + ((4 - (bs & 3)) & 3);
  const int a1 = a0 + (((be - a0) >> 2) << 2);
  for (int i = bs + t; i < min(a0, be); i += 256)
    atomicAdd(&cnt[packed[i] >> 24], 1);
  const uint4* p4 = reinterpret_cast<const uint4*>(packed + a0);
  const int nv = (a1 - a0) >> 2;
  for (int q = t; q < nv; q += 256) {
    uint4 p = p4[q];
    atomicAdd(&cnt[p.x >> 24], 1); atomicAdd(&cnt[p.y >> 24], 1);
    atomicAdd(&cnt[p.z >> 24], 1); atomicAdd(&cnt[p.w >> 24], 1);
  }
  for (int i = max(a1, bs) + t; i < be; i += 256)
    atomicAdd(&cnt[packed[i] >> 24], 1);
  __syncthreads();
  int own = cnt[t];
  tmp[t] = own;
  __syncthreads();
  for (int off = 1; off < NPB; off <<= 1) {
    int x = (t >= off) ? tmp[t - off] : 0;
    __syncthreads();
    tmp[t] += x;
    __syncthreads();
  }
  const int pref = tmp[t] - own;
  if (v0 + t < N) {
    row_st[v0 + t] = bs + pref;
    ni[v0 + t] = rsqrtf(fmaxf((float)own, 1.0f));
  }
  cur[t] = bs + pref;
  __syncthreads();
  for (int i = bs + t; i < min(a0, be); i += 256) {
    unsigned int p = packed[i];
    int pos = atomicAdd(&cur[p >> 24], 1);
    edge_src[pos] = (int)(p & 0xFFFFFFu);
  }
  for (int q = t; q < nv; q += 256) {
    uint4 p = p4[q];
#pragma unroll
    for (int k = 0; k < 4; ++k) {
      unsigned int pv = (&p.x)[k];
      int pos = atomicAdd(&cur[pv >> 24], 1);
      edge_src[pos] = (int)(pv & 0xFFFFFFu);
    }
  }
  for (int i = max(a1, bs) + t; i < be; i += 256) {
    unsigned int p = packed[i];
    int pos = atomicAdd(&cur[p >> 24], 1);
    edge_src[pos] = (int)(p & 0xFFFFFFu);
  }
}

// ========= passD: per-src-bucket count -> norm_o (no global atomics) ======
__global__ __launch_bounds__(256) void passD_kernel(
    const unsigned char* __restrict__ srcS, const int* __restrict__ bkt_stS,
    float* __restrict__ no, int N) {
  __shared__ int cnt[NPB];
  const int b = blockIdx.x;
  const int t = threadIdx.x;
  cnt[t] = 0;
  __syncthreads();
  const int bs = bkt_stS[b];
  const int be = bkt_stS[b + 1];
  for (int i = bs + t; i < be; i += 256)
    atomicAdd(&cnt[srcS[i]], 1);
  __syncthreads();
  const int v = b * NPB + t;
  if (v < N) no[v] = rsqrtf(fmaxf((float)cnt[t], 1.0f));
}

// ===================== weight transpose + f16 convert =====================
__global__ void wconv_kernel(const float* __restrict__ W, unsigned short* __restrict__ Wt,
                             int K, int C) {
  int i = blockIdx.x * blockDim.x + threadIdx.x;
  if (i < K * C) {
    int k = i / C, c = i - k * C;
    Wt[c * K + k] = f2h(W[i]);
  }
}

// ============= feats f32 -> f16 with norm_o fold: out = no[r]*F[r][c] =====
__global__ __launch_bounds__(256) void featconv_kernel(const float* __restrict__ F,
                                                       const float* __restrict__ no,
                                                       unsigned short* __restrict__ out, int N) {
  int row = blockIdx.x * 8 + (threadIdx.x >> 5);
  if (row >= N) return;
  int c = (threadIdx.x & 31) * 4;
  float4 v = *reinterpret_cast<const float4*>(F + (size_t)row * 128 + c);
  float nof = no[row];
  uint2 p = {pk2h(v.x * nof, v.y * nof), pk2h(v.z * nof, v.w * nof)};
  *reinterpret_cast<uint2*>(out + (size_t)row * 128 + c) = p;
}

// ============== gather aggregation, 128-wide, fp16 packed adds ============
__global__ __launch_bounds__(256) void gather_agg_h(
    const unsigned short* __restrict__ hH, const int* __restrict__ row_start,
    const int* __restrict__ edge_src, const float* __restrict__ ni,
    unsigned short* __restrict__ aggH, int N) {
  const int v = blockIdx.x * 4 + (threadIdx.x >> 6);
  if (v >= N) return;
  const int l = threadIdx.x & 63;
  const int half = l >> 5;
  const int lane = l & 31;
  const int s = row_start[v];
  const int e = row_start[v + 1];
  const int co = 4 * lane;
  const __half2 z = __float2half2_rn(0.f);
  __half2 A0 = z, A1 = z, B0 = z, B1 = z, C0 = z, C1 = z, D0 = z, D1 = z;
  int j = s;
  for (; j + 8 <= e; j += 8) {
    int u0 = edge_src[j + half];
    int u1 = edge_src[j + 2 + half];
    int u2 = edge_src[j + 4 + half];
    int u3 = edge_src[j + 6 + half];
    uint2 p0 = *reinterpret_cast<const uint2*>(hH + (size_t)u0 * 128 + co);
    uint2 p1 = *reinterpret_cast<const uint2*>(hH + (size_t)u1 * 128 + co);
    uint2 p2 = *reinterpret_cast<const uint2*>(hH + (size_t)u2 * 128 + co);
    uint2 p3 = *reinterpret_cast<const uint2*>(hH + (size_t)u3 * 128 + co);
    A0 = __hadd2(A0, u2h2(p0.x)); A1 = __hadd2(A1, u2h2(p0.y));
    B0 = __hadd2(B0, u2h2(p1.x)); B1 = __hadd2(B1, u2h2(p1.y));
    C0 = __hadd2(C0, u2h2(p2.x)); C1 = __hadd2(C1, u2h2(p2.y));
    D0 = __hadd2(D0, u2h2(p3.x)); D1 = __hadd2(D1, u2h2(p3.y));
  }
  for (; j + 2 <= e; j += 2) {
    int u0 = edge_src[j + half];
    uint2 p0 = *reinterpret_cast<const uint2*>(hH + (size_t)u0 * 128 + co);
    A0 = __hadd2(A0, u2h2(p0.x)); A1 = __hadd2(A1, u2h2(p0.y));
  }
  if (j < e && half == 0) {
    int u0 = edge_src[j];
    uint2 p0 = *reinterpret_cast<const uint2*>(hH + (size_t)u0 * 128 + co);
    A0 = __hadd2(A0, u2h2(p0.x)); A1 = __hadd2(A1, u2h2(p0.y));
  }
  float a0 = (__low2float(A0) + __low2float(B0)) + (__low2float(C0) + __low2float(D0));
  float a1 = (__high2float(A0) + __high2float(B0)) + (__high2float(C0) + __high2float(D0));
  float a2 = (__low2float(A1) + __low2float(B1)) + (__low2float(C1) + __low2float(D1));
  float a3 = (__high2float(A1) + __high2float(B1)) + (__high2float(C1) + __high2float(D1));
  a0 += __shfl_xor(a0, 32);
  a1 += __shfl_xor(a1, 32);
  a2 += __shfl_xor(a2, 32);
  a3 += __shfl_xor(a3, 32);
  if (half == 0) {
    const float niv = ni[v];
    uint2 po = {pk2h(a0 * niv, a1 * niv), pk2h(a2 * niv, a3 * niv)};
    *reinterpret_cast<uint2*>(aggH + (size_t)v * 128 + co) = po;
  }
}

// ====== final gather, 64-wide: out[v] = ni[v]*sum z[u] + b2  (f32 out) ====
__global__ __launch_bounds__(256) void gather_out(
    const unsigned short* __restrict__ zH, const int* __restrict__ row_start,
    const int* __restrict__ edge_src, const float* __restrict__ ni,
    const float* __restrict__ bias, float* __restrict__ out, int N) {
  const int v = blockIdx.x * 4 + (threadIdx.x >> 6);
  if (v >= N) return;
  const int l = threadIdx.x & 63;
  const int half = l >> 5;
  const int lane = l & 31;
  const int s = row_start[v];
  const int e = row_start[v + 1];
  const int co = 2 * lane;
  const __half2 z = __float2half2_rn(0.f);
  __half2 A = z, B = z, C = z, D = z;
  int j = s;
  for (; j + 8 <= e; j += 8) {
    int u0 = edge_src[j + half];
    int u1 = edge_src[j + 2 + half];
    int u2 = edge_src[j + 4 + half];
    int u3 = edge_src[j + 6 + half];
    A = __hadd2(A, u2h2(*reinterpret_cast<const unsigned int*>(zH + (size_t)u0 * 64 + co)));
    B = __hadd2(B, u2h2(*reinterpret_cast<const unsigned int*>(zH + (size_t)u1 * 64 + co)));
    C = __hadd2(C, u2h2(*reinterpret_cast<const unsigned int*>(zH + (size_t)u2 * 64 + co)));
    D = __hadd2(D, u2h2(*reinterpret_cast<const unsigned int*>(zH + (size_t)u3 * 64 + co)));
  }
  for (; j + 2 <= e; j += 2) {
    int u0 = edge_src[j + half];
    A = __hadd2(A, u2h2(*reinterpret_cast<const unsigned int*>(zH + (size_t)u0 * 64 + co)));
  }
  if (j < e && half == 0) {
    int u0 = edge_src[j];
    A = __hadd2(A, u2h2(*reinterpret_cast<const unsigned int*>(zH + (size_t)u0 * 64 + co)));
  }
  float a0 = (__low2float(A) + __low2float(B)) + (__low2float(C) + __low2float(D));
  float a1 = (__high2float(A) + __high2float(B)) + (__high2float(C) + __high2float(D));
  a0 += __shfl_xor(a0, 32);
  a1 += __shfl_xor(a1, 32);
  if (half == 0) {
    const float niv = ni[v];
    float2 bb = *reinterpret_cast<const float2*>(bias + co);
    float2 w = {a0 * niv + bb.x, a1 * niv + bb.y};
    *reinterpret_cast<float2*>(out + (size_t)v * 64 + co) = w;
  }
}

// ====== MFMA matmul [N,128]x[128,128] + bias + LN + ReLU + no-fold (f16) ==
__global__ __launch_bounds__(256) void mm_mfma_ln(
    const unsigned short* __restrict__ A, const unsigned short* __restrict__ Wt,
    const float* __restrict__ b, const float* __restrict__ g,
    const float* __restrict__ be, const float* __restrict__ no,
    unsigned short* __restrict__ out, int N) {
  __shared__ float sS[2][2][16];
  __shared__ float sQ[2][2][16];
  __shared__ float sNo[32];
  const int rbase = blockIdx.x * 32;
  const int w = threadIdx.x >> 6;
  const int l = threadIdx.x & 63;
  const int rt = w & 1, ch = w >> 1;
  if (threadIdx.x < 32) sNo[threadIdx.x] = no[min(rbase + (int)threadIdx.x, N - 1)];
  const int arow = min(rbase + rt * 16 + (l & 15), N - 1);
  const int kof = (l >> 4) * 8;

  f16x8 af[4];
  const unsigned short* ap = A + (size_t)arow * 128 + kof;
#pragma unroll
  for (int kk = 0; kk < 4; ++kk)
    af[kk] = *reinterpret_cast<const f16x8*>(ap + kk * 32);

  f32x4 acc[4] = {};
#pragma unroll
  for (int ct = 0; ct < 4; ++ct) {
    const int ccol = ch * 64 + ct * 16 + (l & 15);
    const unsigned short* bp = Wt + (size_t)ccol * 128 + kof;
#pragma unroll
    for (int kk = 0; kk < 4; ++kk) {
      f16x8 bfr = *reinterpret_cast<const f16x8*>(bp + kk * 32);
      acc[ct] = __builtin_amdgcn_mfma_f32_16x16x32_f16(af[kk], bfr, acc[ct], 0, 0, 0);
    }
  }

  float s[4] = {0.f, 0.f, 0.f, 0.f}, q[4] = {0.f, 0.f, 0.f, 0.f};
#pragma unroll
  for (int ct = 0; ct < 4; ++ct) {
    const float bc = b[ch * 64 + ct * 16 + (l & 15)];
#pragma unroll
    for (int j = 0; j < 4; ++j) {
      float v = acc[ct][j] + bc;
      acc[ct][j] = v;
      s[j] += v;
      q[j] += v * v;
    }
  }
#pragma unroll
  for (int j = 0; j < 4; ++j) {
#pragma unroll
    for (int off = 1; off < 16; off <<= 1) {
      s[j] += __shfl_xor(s[j], off);
      q[j] += __shfl_xor(q[j], off);
    }
  }
  const int grp = l >> 4;
  if ((l & 15) == 0) {
#pragma unroll
    for (int j = 0; j < 4; ++j) {
      sS[rt][ch][grp * 4 + j] = s[j];
      sQ[rt][ch][grp * 4 + j] = q[j];
    }
  }
  __syncthreads();

#pragma unroll
  for (int j = 0; j < 4; ++j) {
    const int r = grp * 4 + j;
    const int row = rbase + rt * 16 + r;
    float S = sS[rt][0][r] + sS[rt][1][r];
    float Q = sQ[rt][0][r] + sQ[rt][1][r];
    float mu = S * (1.f / 128.f);
    float rstd = rsqrtf(fmaxf(Q * (1.f / 128.f) - mu * mu, 0.f) + LN_EPS);
    float nof = sNo[rt * 16 + r];
    if (row < N) {
#pragma unroll
      for (int ct = 0; ct < 4; ++ct) {
        const int ccol = ch * 64 + ct * 16 + (l & 15);
        float y = (acc[ct][j] - mu) * rstd * g[ccol] + be[ccol];
        y = fmaxf(y, 0.f) * nof;
        out[(size_t)row * 128 + ccol] = f2h(y);
      }
    }
  }
}

// ==== fused layer-1: mm+bias+LN+ReLU+no-fold -> LDS tile -> z = h'@W2 =====
// Writes ONLY zH [N,64] (h' never hits global memory).
__global__ __launch_bounds__(256) void mm_ln_z(
    const unsigned short* __restrict__ A, const unsigned short* __restrict__ Wt,
    const float* __restrict__ b, const float* __restrict__ g,
    const float* __restrict__ be, const float* __restrict__ no,
    const unsigned short* __restrict__ Wt2, unsigned short* __restrict__ zH, int N) {
  __shared__ float sS[2][2][16];
  __shared__ float sQ[2][2][16];
  __shared__ float sNo[32];
  __shared__ unsigned short ht[32][136];  // +8 pad
  const int rbase = blockIdx.x * 32;
  const int w = threadIdx.x >> 6;
  const int l = threadIdx.x & 63;
  const int rt = w & 1, ch = w >> 1;
  if (threadIdx.x < 32) sNo[threadIdx.x] = no[min(rbase + (int)threadIdx.x, N - 1)];
  const int arow = min(rbase + rt * 16 + (l & 15), N - 1);
  const int kof = (l >> 4) * 8;

  f16x8 af[4];
  const unsigned short* ap = A + (size_t)arow * 128 + kof;
#pragma unroll
  for (int kk = 0; kk < 4; ++kk)
    af[kk] = *reinterpret_cast<const f16x8*>(ap + kk * 32);

  f32x4 acc[4] = {};
#pragma unroll
  for (int ct = 0; ct < 4; ++ct) {
    const int ccol = ch * 64 + ct * 16 + (l & 15);
    const unsigned short* bp = Wt + (size_t)ccol * 128 + kof;
#pragma unroll
    for (int kk = 0; kk < 4; ++kk) {
      f16x8 bfr = *reinterpret_cast<const f16x8*>(bp + kk * 32);
      acc[ct] = __builtin_amdgcn_mfma_f32_16x16x32_f16(af[kk], bfr, acc[ct], 0, 0, 0);
    }
  }

  float s[4] = {0.f, 0.f, 0.f, 0.f}, q[4] = {0.f, 0.f, 0.f, 0.f};
#pragma unroll
  for (int ct = 0; ct < 4; ++ct) {
    const float bc = b[ch * 64 + ct * 16 + (l & 15)];
#pragma unroll
    for (int j = 0; j < 4; ++j) {
      float v = acc[ct][j] + bc;
      acc[ct][j] = v;
      s[j] += v;
      q[j] += v * v;
    }
  }
#pragma unroll
  for (int j = 0; j < 4; ++j) {
#pragma unroll
    for (int off = 1; off < 16; off <<= 1) {
      s[j] += __shfl_xor(s[j], off);
      q[j] += __shfl_xor(q[j], off);
    }
  }
  const int grp = l >> 4;
  if ((l & 15) == 0) {
#pragma unroll
    for (int j = 0; j < 4; ++j) {
      sS[rt][ch][grp * 4 + j] = s[j];
      sQ[rt][ch][grp * 4 + j] = q[j];
    }
  }
  __syncthreads();

#pragma unroll
  for (int j = 0; j < 4; ++j) {
    const int r = grp * 4 + j;
    float S = sS[rt][0][r] + sS[rt][1][r];
    float Q = sQ[rt][0][r] + sQ[rt][1][r];
    float mu = S * (1.f / 128.f);
    float rstd = rsqrtf(fmaxf(Q * (1.f / 128.f) - mu * mu, 0.f) + LN_EPS);
    float nof = sNo[rt * 16 + r];
#pragma unroll
    for (int ct = 0; ct < 4; ++ct) {
      const int ccol = ch * 64 + ct * 16 + (l & 15);
      float y = (acc[ct][j] - mu) * rstd * g[ccol] + be[ccol];
      y = fmaxf(y, 0.f) * nof;
      ht[rt * 16 + r][ccol] = f2h(y);
    }
  }
  __syncthreads();

  // stage 2: z-tile = ht @ W2 (128 -> 64)
  f16x8 af2[4];
#pragma unroll
  for (int kk = 0; kk < 4; ++kk)
    af2[kk] = *reinterpret_cast<const f16x8*>(&ht[rt * 16 + (l & 15)][kof + kk * 32]);

  f32x4 acc2[2] = {};
#pragma unroll
  for (int ct = 0; ct < 2; ++ct) {
    const int ccol = ch * 32 + ct * 16 + (l & 15);
    const unsigned short* bp = Wt2 + (size_t)ccol * 128 + kof;
#pragma unroll
    for (int kk = 0; kk < 4; ++kk) {
      f16x8 bfr = *reinterpret_cast<const f16x8*>(bp + kk * 32);
      acc2[ct] = __builtin_amdgcn_mfma_f32_16x16x32_f16(af2[kk], bfr, acc2[ct], 0, 0, 0);
    }
  }
#pragma unroll
  for (int ct = 0; ct < 2; ++ct) {
    const int ccol = ch * 32 + ct * 16 + (l & 15);
#pragma unroll
    for (int j = 0; j < 4; ++j) {
      const int row = rbase + rt * 16 + grp * 4 + j;
      if (row < N) zH[(size_t)row * 64 + ccol] = f2h(acc2[ct][j]);
    }
  }
}

extern "C" void kernel_launch(void* const* d_in, const int* in_sizes, int n_in,
                              void* d_out, int out_size, void* d_ws, size_t ws_size,
                              hipStream_t stream) {
  const float* feats = (const float*)d_in[0];
  const int*   src   = (const int*)d_in[1];
  const int*   dst   = (const int*)d_in[2];
  const float* W0    = (const float*)d_in[3];
  const float* b0    = (const float*)d_in[4];
  const float* g0    = (const float*)d_in[5];
  const float* be0   = (const float*)d_in[6];
  const float* W1    = (const float*)d_in[7];
  const float* b1    = (const float*)d_in[8];
  const float* g1    = (const float*)d_in[9];
  const float* be1   = (const float*)d_in[10];
  const float* W2    = (const float*)d_in[11];
  const float* b2    = (const float*)d_in[12];
  float* out = (float*)d_out;

  const int n = in_sizes[0] / 128;  // 100000
  const int e = in_sizes[1];        // 1600000
  const int NB = (n + NPB - 1) / NPB;        // 391 buckets
  const int NBLK = (e + CHUNK - 1) / CHUNK;  // 391 chunks

  float* ws = (float*)d_ws;
  auto pad4 = [](size_t x) { return (x + 3) & ~(size_t)3; };
  size_t o = 0;
  float* norm_o  = ws + o; o = pad4(o + n);
  float* norm_i  = ws + o; o = pad4(o + n);
  int*   cntD    = (int*)(ws + o); o = pad4(o + (size_t)NB * NBLK);
  int*   cntS    = (int*)(ws + o); o = pad4(o + (size_t)NB * NBLK);
  int*   offLD   = (int*)(ws + o); o = pad4(o + (size_t)NB * NBLK);
  int*   offLS   = (int*)(ws + o); o = pad4(o + (size_t)NB * NBLK);
  int*   totD    = (int*)(ws + o); o = pad4(o + NB);
  int*   totS    = (int*)(ws + o); o = pad4(o + NB);
  int*   bkt_stD = (int*)(ws + o); o = pad4(o + NB + 1);
  int*   bkt_stS = (int*)(ws + o); o = pad4(o + NB + 1);
  int*   row_st  = (int*)(ws + o); o = pad4(o + n + 1);
  unsigned int*  packedD = (unsigned int*)(ws + o);  o = pad4(o + (size_t)e);
  unsigned char* srcS    = (unsigned char*)(ws + o); o = pad4(o + (size_t)(e + 3) / 4);
  int*   edg_src = (int*)(ws + o); o = pad4(o + (size_t)e);
  unsigned short* featH = (unsigned short*)(ws + o); o = pad4(o + (size_t)n * 64);  // also hH
  unsigned short* aggH  = (unsigned short*)(ws + o); o = pad4(o + (size_t)n * 64);
  unsigned short* zH    = (unsigned short*)(ws + o); o = pad4(o + (size_t)n * 32);
  unsigned short* Wt0   = (unsigned short*)(ws + o); o = pad4(o + 128 * 128 / 2);
  unsigned short* Wt1   = (unsigned short*)(ws + o); o = pad4(o + 128 * 128 / 2);
  unsigned short* Wt2   = (unsigned short*)(ws + o); o = pad4(o + 128 * 64 / 2);
  unsigned short* hH = featH;  // featH dead after layer-0 gather

  // ---- CSR build: atomic-free radix partition ----
  passA_kernel<<<NBLK, 256, 2 * NB * sizeof(int), stream>>>(src, dst, cntD, cntS, NB, NBLK, e);
  scan1_kernel<<<2 * NB, 512, 0, stream>>>(cntD, cntS, offLD, offLS, totD, totS, NB, NBLK);
  scan2_kernel<<<1, 512, 0, stream>>>(totD, totS, bkt_stD, bkt_stS, row_st, NB, n, e);
  passB_kernel<<<NBLK, 256, 0, stream>>>(src, dst, cntD, cntS, offLD, offLS, bkt_stD, bkt_stS,
                                         packedD, srcS, NB, NBLK, e);
  passC_kernel<<<NB, 256, 0, stream>>>(packedD, bkt_stD, row_st, norm_i, edg_src, n);
  passD_kernel<<<NB, 256, 0, stream>>>(srcS, bkt_stS, norm_o, n);

  // ---- weights -> f16 transposed; feats -> f16 with no-fold ----
  wconv_kernel<<<(128 * 128 + 255) / 256, 256, 0, stream>>>(W0, Wt0, 128, 128);
  wconv_kernel<<<(128 * 128 + 255) / 256, 256, 0, stream>>>(W1, Wt1, 128, 128);
  wconv_kernel<<<(128 * 64 + 255) / 256, 256, 0, stream>>>(W2, Wt2, 128, 64);
  featconv_kernel<<<(n + 7) / 8, 256, 0, stream>>>(feats, norm_o, featH, n);

  const int gblocks = (n + 3) / 4;
  const int mblocks = (n + 31) / 32;

  // layer 0
  gather_agg_h<<<gblocks, 256, 0, stream>>>(featH, row_st, edg_src, norm_i, aggH, n);
  mm_mfma_ln<<<mblocks, 256, 0, stream>>>(aggH, Wt0, b0, g0, be0, norm_o, hH, n);
  // layer 1 (fused with commuted final matmul) -> zH only
  gather_agg_h<<<gblocks, 256, 0, stream>>>(hH, row_st, edg_src, norm_i, aggH, n);
  mm_ln_z<<<mblocks, 256, 0, stream>>>(aggH, Wt1, b1, g1, be1, norm_o, Wt2, zH, n);
  // final: 64-wide gather + bias -> f32 out
  gather_out<<<gblocks, 256, 0, stream>>>(zH, row_st, edg_src, norm_i, b2, out, n);
}